// Round 4
// baseline (1171.007 us; speedup 1.0000x reference)
//
#include <hip/hip_runtime.h>

#define N_NODES 50000
#define N_EDGES 800000
#define NODE_IN 256
#define EDGE_IN 64
#define HID 128
#define OUTD 16
#define LN_EPS 1e-5f
#define NCHUNK 128
#define EPC (N_EDGES / NCHUNK)   // 6250 edges per chunk

typedef __attribute__((ext_vector_type(4))) float f32x4;
typedef __attribute__((ext_vector_type(8))) _Float16 half8;
typedef __attribute__((ext_vector_type(4))) _Float16 half4;

__device__ __forceinline__ float gelu_exact(float x) {
    return 0.5f * x * (1.0f + erff(x * 0.70710678118654752f));
}

// ---------------------------------------------------------------------------
// Zero the histogram with a kernel (capture-safe by construction).
// ---------------------------------------------------------------------------
__global__ __launch_bounds__(256) void zero_kernel(int4* __restrict__ p, int n4) {
    int i = blockIdx.x * 256 + threadIdx.x;
    const int stride = gridDim.x * 256;
    for (; i < n4; i += stride) p[i] = make_int4(0, 0, 0, 0);
}

// ---------------------------------------------------------------------------
// Setup: transpose weights to [col][k] fp16 (MFMA B fragments become 16B loads)
// ---------------------------------------------------------------------------
__global__ void setup_kernel(const float* __restrict__ Wn, const float* __restrict__ We,
                             _Float16* __restrict__ WTn, _Float16* __restrict__ WTe) {
    int t = blockIdx.x * blockDim.x + threadIdx.x;
    int stride = gridDim.x * blockDim.x;
    for (int i = t; i < HID * NODE_IN; i += stride) {
        int n = i >> 8, k = i & 255;
        WTn[i] = (_Float16)Wn[k * HID + n];
    }
    for (int i = t; i < HID * EDGE_IN; i += stride) {
        int n = i >> 6, k = i & 63;
        WTe[i] = (_Float16)We[k * HID + n];
    }
}

// ---------------------------------------------------------------------------
// Deterministic stable counting sort by dst.
// ---------------------------------------------------------------------------
__global__ __launch_bounds__(256) void hist_kernel(const int* __restrict__ dst,
                                                   int* __restrict__ hist) {
    const int k = blockIdx.x >> 2;
    const int part = blockIdx.x & 3;
    int* hk = hist + k * N_NODES;
    const int beg = k * EPC;
    for (int i = part * 256 + threadIdx.x; i < EPC; i += 1024)
        atomicAdd(&hk[dst[beg + i]], 1);
}

__global__ __launch_bounds__(256) void tot_kernel(const int* __restrict__ hist,
                                                  int* __restrict__ tot) {
    int n = blockIdx.x * 256 + threadIdx.x;
    if (n < N_NODES) {
        int s = 0;
        #pragma unroll 8
        for (int k = 0; k < NCHUNK; ++k) s += hist[k * N_NODES + n];
        tot[n] = s;
    }
}

__global__ __launch_bounds__(256) void scan1_kernel(const int* __restrict__ tot,
                                                    int* __restrict__ offs,
                                                    int* __restrict__ btot) {
    __shared__ int lsum[256];
    const int t = threadIdx.x;
    const int base = blockIdx.x * 1024 + t * 4;
    int v[4]; int s = 0;
    #pragma unroll
    for (int j = 0; j < 4; ++j) {
        int idx = base + j;
        v[j] = (idx < N_NODES) ? tot[idx] : 0;
        s += v[j];
    }
    lsum[t] = s;
    __syncthreads();
    for (int d = 1; d < 256; d <<= 1) {
        int x = (t >= d) ? lsum[t - d] : 0;
        __syncthreads();
        lsum[t] += x;
        __syncthreads();
    }
    int excl = lsum[t] - s;
    if (t == 255) btot[blockIdx.x] = lsum[255];
    int run = excl;
    #pragma unroll
    for (int j = 0; j < 4; ++j) {
        int idx = base + j;
        if (idx < N_NODES) offs[idx] = run;
        run += v[j];
    }
}

__global__ __launch_bounds__(256) void scan2_kernel(int* __restrict__ offs,
                                                    const int* __restrict__ btot) {
    int s = 0;
    for (int i = 0; i < (int)blockIdx.x; ++i) s += btot[i];
    const int t = threadIdx.x;
    const int base = blockIdx.x * 1024 + t * 4;
    #pragma unroll
    for (int j = 0; j < 4; ++j) {
        int idx = base + j;
        if (idx < N_NODES) offs[idx] += s;
    }
    if (blockIdx.x == 0 && t == 0) offs[N_NODES] = N_EDGES;
}

__global__ __launch_bounds__(256) void cursor_kernel(const int* __restrict__ offs,
                                                     int* __restrict__ hist) {
    int n = blockIdx.x * 256 + threadIdx.x;
    if (n < N_NODES) {
        int running = offs[n];
        #pragma unroll 4
        for (int k = 0; k < NCHUNK; ++k) {
            int c = hist[k * N_NODES + n];
            hist[k * N_NODES + n] = running;
            running += c;
        }
    }
}

__global__ __launch_bounds__(256) void place_kernel(const int* __restrict__ src,
                                                    const int* __restrict__ dst,
                                                    int* __restrict__ cur,
                                                    int* __restrict__ perm,
                                                    int* __restrict__ psrc,
                                                    int* __restrict__ spos) {
    __shared__ int ld[256];
    __shared__ int ls[256];
    __shared__ int lb[256];
    const int k = blockIdx.x;
    const int t = threadIdx.x;
    int* curk = cur + k * N_NODES;
    const int cbeg = k * EPC;
    const int ngroups = (EPC + 255) / 256;
    for (int g = 0; g < ngroups; ++g) {
        const int gbeg = cbeg + g * 256;
        const int count = min(256, cbeg + EPC - gbeg);
        __syncthreads();
        if (t < count) { ld[t] = dst[gbeg + t]; ls[t] = src[gbeg + t]; }
        __syncthreads();
        int rank = 0, leader = -1, total = 0;
        const int d = (t < count) ? ld[t] : -1;
        if (t < count) {
            #pragma unroll 4
            for (int i = 0; i < count; ++i) {
                bool m = (ld[i] == d);
                total += m;
                rank += (m && i < t);
                if (m && leader < 0) leader = i;
            }
            if (rank == 0) {
                int bse = curk[d];
                curk[d] = bse + total;
                lb[t] = bse;
            }
        }
        __syncthreads();
        if (t < count) {
            int pos = lb[leader] + rank;
            perm[pos] = gbeg + t;
            psrc[pos] = ls[t];
            spos[gbeg + t] = pos;
        }
    }
}

// ---------------------------------------------------------------------------
// Node projection: hv = LN(GELU(X @ Wn)), stored fp16 PERMUTED:
// hv[row*128 + x*8 + c] = value at col (16c + x).
// ---------------------------------------------------------------------------
__global__ __launch_bounds__(256) void node_kernel(
    const float* __restrict__ X,
    const _Float16* __restrict__ WT,    // [HID][NODE_IN]
    const float* __restrict__ g, const float* __restrict__ b,
    _Float16* __restrict__ hv)
{
    __shared__ __align__(16) _Float16 lA[64 * 72];
    __shared__ __align__(16) _Float16 lB[128 * 72];

    const int t = threadIdx.x;
    const int wave = t >> 6, lane = t & 63;
    const int x15 = lane & 15, quad = lane >> 4;
    const int row0 = blockIdx.x * 64;

    float gc[8], bc[8];
    #pragma unroll
    for (int c = 0; c < 8; ++c) { gc[c] = g[16 * c + x15]; bc[c] = b[16 * c + x15]; }

    f32x4 acc[8];
    #pragma unroll
    for (int c = 0; c < 8; ++c) acc[c] = (f32x4)(0.0f);

    for (int kc = 0; kc < 4; ++kc) {
        const int k0 = kc * 64;
        __syncthreads();
        #pragma unroll
        for (int j = 0; j < 4; ++j) {
            int idx = j * 1024 + t * 4;
            int r = idx >> 6, kk = idx & 63;
            int grow = row0 + r;
            float4 v = make_float4(0.f, 0.f, 0.f, 0.f);
            if (grow < N_NODES) v = *(const float4*)(X + grow * NODE_IN + k0 + kk);
            half4 h4;
            h4[0] = (_Float16)v.x; h4[1] = (_Float16)v.y;
            h4[2] = (_Float16)v.z; h4[3] = (_Float16)v.w;
            *(half4*)(lA + r * 72 + kk) = h4;
        }
        #pragma unroll
        for (int j = 0; j < 4; ++j) {
            int idx = j * 2048 + t * 8;
            int n = idx >> 6, kk = idx & 63;
            half8 v = *(const half8*)(WT + n * NODE_IN + k0 + kk);
            *(half8*)(lB + n * 72 + kk) = v;
        }
        __syncthreads();
        #pragma unroll
        for (int ks = 0; ks < 2; ++ks) {
            half8 a = *(const half8*)(lA + (wave * 16 + x15) * 72 + ks * 32 + quad * 8);
            #pragma unroll
            for (int c = 0; c < 8; ++c) {
                half8 bb = *(const half8*)(lB + (c * 16 + x15) * 72 + ks * 32 + quad * 8);
                acc[c] = __builtin_amdgcn_mfma_f32_16x16x32_f16(a, bb, acc[c], 0, 0, 0);
            }
        }
    }

    float v[8][4], s[4], sq[4];
    #pragma unroll
    for (int r = 0; r < 4; ++r) { s[r] = 0.f; sq[r] = 0.f; }
    #pragma unroll
    for (int c = 0; c < 8; ++c)
        #pragma unroll
        for (int r = 0; r < 4; ++r) {
            float x = gelu_exact(acc[c][r]);
            v[c][r] = x; s[r] += x; sq[r] += x * x;
        }
    #pragma unroll
    for (int m = 1; m <= 8; m <<= 1)
        #pragma unroll
        for (int r = 0; r < 4; ++r) {
            s[r]  += __shfl_xor(s[r],  m, 64);
            sq[r] += __shfl_xor(sq[r], m, 64);
        }
    #pragma unroll
    for (int r = 0; r < 4; ++r) {
        int row = row0 + wave * 16 + quad * 4 + r;
        if (row >= N_NODES) continue;
        float mean = s[r] * (1.f / 128.f);
        float var  = sq[r] * (1.f / 128.f) - mean * mean;
        float rstd = rsqrtf(var + LN_EPS);
        half8 o;
        #pragma unroll
        for (int c = 0; c < 8; ++c)
            o[c] = (_Float16)((v[c][r] - mean) * rstd * gc[c] + bc[c]);
        *(half8*)(hv + row * HID + x15 * 8) = o;
    }
}

// ---------------------------------------------------------------------------
// Fused aggregation: per node-wave, recompute he = exp(LN(EF@We)) for its
// incoming edges (16-edge MFMA batches via perm gather) and accumulate
// he * hv[src] in fp32.  Pure, fixed-order, no ws_size dependence.
// ---------------------------------------------------------------------------
__global__ __launch_bounds__(256) void agg_kernel(
    const float* __restrict__ EF,
    const int* __restrict__ perm, const int* __restrict__ psrc,
    const int* __restrict__ offs,
    const _Float16* __restrict__ WT,
    const float* __restrict__ g, const float* __restrict__ b,
    const _Float16* __restrict__ hv,
    float* __restrict__ h)
{
    const int t = threadIdx.x;
    const int wave = t >> 6, lane = t & 63;
    const int x15 = lane & 15, quad = lane >> 4;
    const int n = blockIdx.x * 4 + wave;

    half8 Bf[8][2];
    #pragma unroll
    for (int c = 0; c < 8; ++c)
        #pragma unroll
        for (int ks = 0; ks < 2; ++ks)
            Bf[c][ks] = *(const half8*)(WT + (c * 16 + x15) * EDGE_IN + ks * 32 + quad * 8);

    float gc[8], bc[8];
    #pragma unroll
    for (int c = 0; c < 8; ++c) { gc[c] = g[16 * c + x15]; bc[c] = b[16 * c + x15]; }

    const int beg = offs[n], end = offs[n + 1];

    f32x4 vacc[8];
    #pragma unroll
    for (int c = 0; c < 8; ++c) vacc[c] = (f32x4)(0.0f);

    for (int e0 = beg; e0 < end; e0 += 16) {
        int ea = e0 + x15;
        if (ea >= end) ea = end - 1;
        int pe = perm[ea];
        const float* ep = EF + (size_t)pe * EDGE_IN;

        f32x4 acc[8];
        #pragma unroll
        for (int c = 0; c < 8; ++c) acc[c] = (f32x4)(0.0f);

        #pragma unroll
        for (int ks = 0; ks < 2; ++ks) {
            float4 f0 = *(const float4*)(ep + ks * 32 + quad * 8);
            float4 f1 = *(const float4*)(ep + ks * 32 + quad * 8 + 4);
            half8 a;
            a[0] = (_Float16)f0.x; a[1] = (_Float16)f0.y;
            a[2] = (_Float16)f0.z; a[3] = (_Float16)f0.w;
            a[4] = (_Float16)f1.x; a[5] = (_Float16)f1.y;
            a[6] = (_Float16)f1.z; a[7] = (_Float16)f1.w;
            #pragma unroll
            for (int c = 0; c < 8; ++c)
                acc[c] = __builtin_amdgcn_mfma_f32_16x16x32_f16(a, Bf[c][ks], acc[c], 0, 0, 0);
        }

        float s[4], sq[4];
        #pragma unroll
        for (int r = 0; r < 4; ++r) { s[r] = 0.f; sq[r] = 0.f; }
        #pragma unroll
        for (int c = 0; c < 8; ++c)
            #pragma unroll
            for (int r = 0; r < 4; ++r) { float x = acc[c][r]; s[r] += x; sq[r] += x * x; }
        #pragma unroll
        for (int m = 1; m <= 8; m <<= 1)
            #pragma unroll
            for (int r = 0; r < 4; ++r) {
                s[r]  += __shfl_xor(s[r],  m, 64);
                sq[r] += __shfl_xor(sq[r], m, 64);
            }

        #pragma unroll
        for (int r = 0; r < 4; ++r) {
            int er = e0 + quad * 4 + r;
            if (er < end) {
                int se = psrc[er];
                half8 hg = *(const half8*)(hv + (size_t)se * HID + x15 * 8);
                float mean = s[r] * (1.f / 128.f);
                float var  = sq[r] * (1.f / 128.f) - mean * mean;
                float rstd = rsqrtf(var + LN_EPS);
                #pragma unroll
                for (int c = 0; c < 8; ++c) {
                    float he = __expf((acc[c][r] - mean) * rstd * gc[c] + bc[c]);
                    vacc[c][r] += he * (float)hg[c];
                }
            }
        }
    }

    float o8[8];
    #pragma unroll
    for (int c = 0; c < 8; ++c) {
        float v = vacc[c][0] + vacc[c][1] + vacc[c][2] + vacc[c][3];
        v += __shfl_xor(v, 16, 64);
        v += __shfl_xor(v, 32, 64);
        o8[c] = v;
    }
    if (quad == 0) {
        float* hp = h + (size_t)n * HID + x15 * 8;
        *(float4*)hp = make_float4(o8[0], o8[1], o8[2], o8[3]);
        *(float4*)(hp + 4) = make_float4(o8[4], o8[5], o8[6], o8[7]);
    }
}

// ---------------------------------------------------------------------------
// Out projection: out = LN(GELU(h @ Wout)).  Un-permutes h in LDS staging.
// ---------------------------------------------------------------------------
__global__ __launch_bounds__(256) void out_kernel(
    const float* __restrict__ h,
    const float* __restrict__ W,       // [128][16]
    const float* __restrict__ g, const float* __restrict__ b,
    float* __restrict__ out)
{
    __shared__ float lW[HID * OUTD];
    __shared__ float lh[16][HID];
    const int t = threadIdx.x;
    const int node0 = blockIdx.x * 16;

    for (int i = t; i < HID * OUTD; i += 256) lW[i] = W[i];
    for (int i = t; i < 16 * HID; i += 256) {
        int row = i >> 7, p = i & 127;
        int k = 16 * (p & 7) + (p >> 3);     // un-permute: p = x*8 + c -> k = 16c + x
        int grow = node0 + row;
        lh[row][k] = (grow < N_NODES) ? h[grow * HID + p] : 0.f;
    }
    __syncthreads();

    const int i = t >> 4, j = t & 15;
    float acc = 0.f;
    #pragma unroll 8
    for (int k = 0; k < HID; ++k)
        acc = fmaf(lh[i][k], lW[k * OUTD + j], acc);
    float x = gelu_exact(acc);
    float s = x, sq = x * x;
    #pragma unroll
    for (int m = 1; m <= 8; m <<= 1) {
        s  += __shfl_xor(s,  m, 64);
        sq += __shfl_xor(sq, m, 64);
    }
    float mean = s * (1.f / 16.f);
    float var  = sq * (1.f / 16.f) - mean * mean;
    float rstd = rsqrtf(var + LN_EPS);
    int grow = node0 + i;
    if (grow < N_NODES) out[grow * OUTD + j] = (x - mean) * rstd * g[j] + b[j];
}

// ---------------------------------------------------------------------------
// NOTE: no ws_size-dependent behavior.  A previous version dispatched between
// a two-phase path (materialized he, +205MB ws) and this fused path based on
// ws_size >= need; the two paths are numerically different, so any variation
// in ws_size across harness calls (capture vs direct) made the timed graph
// diverge from launch_once -> tripwire.  One path, unconditionally.
// ---------------------------------------------------------------------------
extern "C" void kernel_launch(void* const* d_in, const int* in_sizes, int n_in,
                              void* d_out, int out_size, void* d_ws, size_t ws_size,
                              hipStream_t stream) {
    const float* node_feats = (const float*)d_in[0];
    const float* edge_feats = (const float*)d_in[1];
    const int*   src        = (const int*)d_in[2];
    const int*   dst        = (const int*)d_in[3];
    const float* W_node     = (const float*)d_in[4];
    const float* g_node     = (const float*)d_in[5];
    const float* b_node     = (const float*)d_in[6];
    const float* W_edge     = (const float*)d_in[7];
    const float* g_edge     = (const float*)d_in[8];
    const float* b_edge     = (const float*)d_in[9];
    const float* W_out      = (const float*)d_in[10];
    const float* g_out      = (const float*)d_in[11];
    const float* b_out      = (const float*)d_in[12];
    float* out = (float*)d_out;

    char* ws = (char*)d_ws;
    size_t o = 0;
    _Float16* hv  = (_Float16*)(ws + o); o += (size_t)N_NODES * HID * 2;        // 12.8 MB
    float*    h   = (float*)(ws + o);    o += (size_t)N_NODES * HID * 4;        // 25.6 MB
    _Float16* WTn = (_Float16*)(ws + o); o += (size_t)HID * NODE_IN * 2;        // 64 KB
    _Float16* WTe = (_Float16*)(ws + o); o += (size_t)HID * EDGE_IN * 2;        // 16 KB
    int* tot  = (int*)(ws + o); o += (size_t)N_NODES * 4;                       // 200 KB
    int* offs = (int*)(ws + o); o += (size_t)(N_NODES + 16) * 4;                // 200 KB
    int* btot = (int*)(ws + o); o += 1024;
    int* hist = (int*)(ws + o); o += (size_t)NCHUNK * N_NODES * 4;              // 25.6 MB
    int* perm = (int*)(ws + o); o += (size_t)N_EDGES * 4;                       // 3.2 MB
    int* psrc = (int*)(ws + o); o += (size_t)N_EDGES * 4;                       // 3.2 MB
    int* spos = (int*)(ws + o); o += (size_t)N_EDGES * 4;                       // 3.2 MB
    (void)spos;  // written by place_kernel; unused downstream in this variant

    zero_kernel<<<2048, 256, 0, stream>>>((int4*)hist, NCHUNK * N_NODES / 4);
    setup_kernel<<<128, 256, 0, stream>>>(W_node, W_edge, WTn, WTe);
    node_kernel<<<(N_NODES + 63) / 64, 256, 0, stream>>>(node_feats, WTn, g_node, b_node, hv);
    hist_kernel<<<NCHUNK * 4, 256, 0, stream>>>(dst, hist);
    tot_kernel<<<(N_NODES + 255) / 256, 256, 0, stream>>>(hist, tot);
    scan1_kernel<<<49, 256, 0, stream>>>(tot, offs, btot);
    scan2_kernel<<<49, 256, 0, stream>>>(offs, btot);
    cursor_kernel<<<(N_NODES + 255) / 256, 256, 0, stream>>>(offs, hist);
    place_kernel<<<NCHUNK, 256, 0, stream>>>(src, dst, hist, perm, psrc, spos);
    agg_kernel<<<N_NODES / 4, 256, 0, stream>>>(edge_feats, perm, psrc, offs, WTe, g_edge, b_edge, hv, h);
    out_kernel<<<(N_NODES + 15) / 16, 256, 0, stream>>>(h, W_out, g_out, b_out, out);
}

// Round 5
// 875.311 us; speedup vs baseline: 1.3378x; 1.3378x over previous
//
#include <hip/hip_runtime.h>

#define N_NODES 50000
#define N_EDGES 800000
#define NODE_IN 256
#define EDGE_IN 64
#define HID 128
#define OUTD 16
#define LN_EPS 1e-5f
#define NCHUNK 128
#define EPC (N_EDGES / NCHUNK)   // 6250 edges per chunk

typedef __attribute__((ext_vector_type(4))) float f32x4;
typedef __attribute__((ext_vector_type(8))) _Float16 half8;
typedef __attribute__((ext_vector_type(4))) _Float16 half4;

__device__ __forceinline__ float gelu_exact(float x) {
    return 0.5f * x * (1.0f + erff(x * 0.70710678118654752f));
}

// ---------------------------------------------------------------------------
// Zero helper (kernel, capture-safe).
// ---------------------------------------------------------------------------
__global__ __launch_bounds__(256) void zero_kernel(int4* __restrict__ p, int n4) {
    int i = blockIdx.x * 256 + threadIdx.x;
    const int stride = gridDim.x * 256;
    for (; i < n4; i += stride) p[i] = make_int4(0, 0, 0, 0);
}

// ---------------------------------------------------------------------------
// Setup: transpose weights to [col][k] fp16 (MFMA B fragments become 16B loads)
// ---------------------------------------------------------------------------
__global__ void setup_kernel(const float* __restrict__ Wn, const float* __restrict__ We,
                             _Float16* __restrict__ WTn, _Float16* __restrict__ WTe) {
    int t = blockIdx.x * blockDim.x + threadIdx.x;
    int stride = gridDim.x * blockDim.x;
    for (int i = t; i < HID * NODE_IN; i += stride) {
        int n = i >> 8, k = i & 255;
        WTn[i] = (_Float16)Wn[k * HID + n];
    }
    for (int i = t; i < HID * EDGE_IN; i += stride) {
        int n = i >> 6, k = i & 63;
        WTe[i] = (_Float16)We[k * HID + n];
    }
}

// ---------------------------------------------------------------------------
// Deterministic stable counting sort by dst.
// ---------------------------------------------------------------------------
__global__ __launch_bounds__(256) void hist_kernel(const int* __restrict__ dst,
                                                   int* __restrict__ hist) {
    const int k = blockIdx.x >> 2;
    const int part = blockIdx.x & 3;
    int* hk = hist + k * N_NODES;
    const int beg = k * EPC;
    for (int i = part * 256 + threadIdx.x; i < EPC; i += 1024)
        atomicAdd(&hk[dst[beg + i]], 1);
}

__global__ __launch_bounds__(256) void tot_kernel(const int* __restrict__ hist,
                                                  int* __restrict__ tot) {
    int n = blockIdx.x * 256 + threadIdx.x;
    if (n < N_NODES) {
        int s = 0;
        #pragma unroll 8
        for (int k = 0; k < NCHUNK; ++k) s += hist[k * N_NODES + n];
        tot[n] = s;
    }
}

__global__ __launch_bounds__(256) void scan1_kernel(const int* __restrict__ tot,
                                                    int* __restrict__ offs,
                                                    int* __restrict__ btot) {
    __shared__ int lsum[256];
    const int t = threadIdx.x;
    const int base = blockIdx.x * 1024 + t * 4;
    int v[4]; int s = 0;
    #pragma unroll
    for (int j = 0; j < 4; ++j) {
        int idx = base + j;
        v[j] = (idx < N_NODES) ? tot[idx] : 0;
        s += v[j];
    }
    lsum[t] = s;
    __syncthreads();
    for (int d = 1; d < 256; d <<= 1) {
        int x = (t >= d) ? lsum[t - d] : 0;
        __syncthreads();
        lsum[t] += x;
        __syncthreads();
    }
    int excl = lsum[t] - s;
    if (t == 255) btot[blockIdx.x] = lsum[255];
    int run = excl;
    #pragma unroll
    for (int j = 0; j < 4; ++j) {
        int idx = base + j;
        if (idx < N_NODES) offs[idx] = run;
        run += v[j];
    }
}

__global__ __launch_bounds__(256) void scan2_kernel(int* __restrict__ offs,
                                                    const int* __restrict__ btot) {
    int s = 0;
    for (int i = 0; i < (int)blockIdx.x; ++i) s += btot[i];
    const int t = threadIdx.x;
    const int base = blockIdx.x * 1024 + t * 4;
    #pragma unroll
    for (int j = 0; j < 4; ++j) {
        int idx = base + j;
        if (idx < N_NODES) offs[idx] += s;
    }
    if (blockIdx.x == 0 && t == 0) offs[N_NODES] = N_EDGES;
}

__global__ __launch_bounds__(256) void cursor_kernel(const int* __restrict__ offs,
                                                     int* __restrict__ hist) {
    int n = blockIdx.x * 256 + threadIdx.x;
    if (n < N_NODES) {
        int running = offs[n];
        #pragma unroll 4
        for (int k = 0; k < NCHUNK; ++k) {
            int c = hist[k * N_NODES + n];
            hist[k * N_NODES + n] = running;
            running += c;
        }
    }
}

// Stable placement.  Also emits pdst[pos] (dst in sorted order) for the
// segmented aggregation; spos/inverse map no longer needed.
__global__ __launch_bounds__(256) void place_kernel(const int* __restrict__ src,
                                                    const int* __restrict__ dst,
                                                    int* __restrict__ cur,
                                                    int* __restrict__ perm,
                                                    int* __restrict__ psrc,
                                                    int* __restrict__ pdst) {
    __shared__ int ld[256];
    __shared__ int ls[256];
    __shared__ int lb[256];
    const int k = blockIdx.x;
    const int t = threadIdx.x;
    int* curk = cur + k * N_NODES;
    const int cbeg = k * EPC;
    const int ngroups = (EPC + 255) / 256;
    for (int g = 0; g < ngroups; ++g) {
        const int gbeg = cbeg + g * 256;
        const int count = min(256, cbeg + EPC - gbeg);
        __syncthreads();
        if (t < count) { ld[t] = dst[gbeg + t]; ls[t] = src[gbeg + t]; }
        __syncthreads();
        int rank = 0, leader = -1, total = 0;
        const int d = (t < count) ? ld[t] : -1;
        if (t < count) {
            #pragma unroll 4
            for (int i = 0; i < count; ++i) {
                bool m = (ld[i] == d);
                total += m;
                rank += (m && i < t);
                if (m && leader < 0) leader = i;
            }
            if (rank == 0) {
                int bse = curk[d];
                curk[d] = bse + total;
                lb[t] = bse;
            }
        }
        __syncthreads();
        if (t < count) {
            int pos = lb[leader] + rank;
            perm[pos] = gbeg + t;
            psrc[pos] = ls[t];
            pdst[pos] = d;
        }
    }
}

// ---------------------------------------------------------------------------
// Node projection: hv = LN(GELU(X @ Wn)), stored fp16 PERMUTED:
// hv[row*128 + x*8 + c] = value at col (16c + x).
// ---------------------------------------------------------------------------
__global__ __launch_bounds__(256) void node_kernel(
    const float* __restrict__ X,
    const _Float16* __restrict__ WT,    // [HID][NODE_IN]
    const float* __restrict__ g, const float* __restrict__ b,
    _Float16* __restrict__ hv)
{
    __shared__ __align__(16) _Float16 lA[64 * 72];
    __shared__ __align__(16) _Float16 lB[128 * 72];

    const int t = threadIdx.x;
    const int wave = t >> 6, lane = t & 63;
    const int x15 = lane & 15, quad = lane >> 4;
    const int row0 = blockIdx.x * 64;

    float gc[8], bc[8];
    #pragma unroll
    for (int c = 0; c < 8; ++c) { gc[c] = g[16 * c + x15]; bc[c] = b[16 * c + x15]; }

    f32x4 acc[8];
    #pragma unroll
    for (int c = 0; c < 8; ++c) acc[c] = (f32x4)(0.0f);

    for (int kc = 0; kc < 4; ++kc) {
        const int k0 = kc * 64;
        __syncthreads();
        #pragma unroll
        for (int j = 0; j < 4; ++j) {
            int idx = j * 1024 + t * 4;
            int r = idx >> 6, kk = idx & 63;
            int grow = row0 + r;
            float4 v = make_float4(0.f, 0.f, 0.f, 0.f);
            if (grow < N_NODES) v = *(const float4*)(X + grow * NODE_IN + k0 + kk);
            half4 h4;
            h4[0] = (_Float16)v.x; h4[1] = (_Float16)v.y;
            h4[2] = (_Float16)v.z; h4[3] = (_Float16)v.w;
            *(half4*)(lA + r * 72 + kk) = h4;
        }
        #pragma unroll
        for (int j = 0; j < 4; ++j) {
            int idx = j * 2048 + t * 8;
            int n = idx >> 6, kk = idx & 63;
            half8 v = *(const half8*)(WT + n * NODE_IN + k0 + kk);
            *(half8*)(lB + n * 72 + kk) = v;
        }
        __syncthreads();
        #pragma unroll
        for (int ks = 0; ks < 2; ++ks) {
            half8 a = *(const half8*)(lA + (wave * 16 + x15) * 72 + ks * 32 + quad * 8);
            #pragma unroll
            for (int c = 0; c < 8; ++c) {
                half8 bb = *(const half8*)(lB + (c * 16 + x15) * 72 + ks * 32 + quad * 8);
                acc[c] = __builtin_amdgcn_mfma_f32_16x16x32_f16(a, bb, acc[c], 0, 0, 0);
            }
        }
    }

    float v[8][4], s[4], sq[4];
    #pragma unroll
    for (int r = 0; r < 4; ++r) { s[r] = 0.f; sq[r] = 0.f; }
    #pragma unroll
    for (int c = 0; c < 8; ++c)
        #pragma unroll
        for (int r = 0; r < 4; ++r) {
            float x = gelu_exact(acc[c][r]);
            v[c][r] = x; s[r] += x; sq[r] += x * x;
        }
    #pragma unroll
    for (int m = 1; m <= 8; m <<= 1)
        #pragma unroll
        for (int r = 0; r < 4; ++r) {
            s[r]  += __shfl_xor(s[r],  m, 64);
            sq[r] += __shfl_xor(sq[r], m, 64);
        }
    #pragma unroll
    for (int r = 0; r < 4; ++r) {
        int row = row0 + wave * 16 + quad * 4 + r;
        if (row >= N_NODES) continue;
        float mean = s[r] * (1.f / 128.f);
        float var  = sq[r] * (1.f / 128.f) - mean * mean;
        float rstd = rsqrtf(var + LN_EPS);
        half8 o;
        #pragma unroll
        for (int c = 0; c < 8; ++c)
            o[c] = (_Float16)((v[c][r] - mean) * rstd * gc[c] + bc[c]);
        *(half8*)(hv + row * HID + x15 * 8) = o;
    }
}

// ---------------------------------------------------------------------------
// Fused sorted-block aggregation.  Block = 64 consecutive SORTED edge
// positions.  Phase 1 (eproj structure): gather EF[perm[pos]], MFMA edge
// projection, LN+exp -> he, multiply by hv[psrc[pos]], store products to LDS.
// Phase 2: per-column segmented reduction over the 64 rows by dst.
// Segments fully owning their dst range -> plain int64 store; fragments of
// block-spanning segments -> int64 fixed-point atomicAdd (commutative, exact,
// deterministic).  h64 is pre-zeroed.  Scale 2^32.
// ---------------------------------------------------------------------------
__global__ __launch_bounds__(256) void fagg_kernel(
    const float* __restrict__ EF,
    const int* __restrict__ perm, const int* __restrict__ psrc,
    const int* __restrict__ pdst, const int* __restrict__ offs,
    const _Float16* __restrict__ WT,
    const float* __restrict__ g, const float* __restrict__ b,
    const _Float16* __restrict__ hv,
    long long* __restrict__ h64)
{
    __shared__ __align__(16) _Float16 lA[64 * 72];
    __shared__ __align__(16) float lprod[64 * 128];   // 32 KB
    __shared__ int lperm[64];
    __shared__ int lsrc[64];
    __shared__ int ldst[64];

    const int t = threadIdx.x;
    const int wave = t >> 6, lane = t & 63;
    const int x15 = lane & 15, quad = lane >> 4;
    const int base = blockIdx.x * 64;               // sorted-position base

    // B fragments in registers (WT is 16KB, L2-hot)
    half8 Bf[8][2];
    #pragma unroll
    for (int c = 0; c < 8; ++c)
        #pragma unroll
        for (int ks = 0; ks < 2; ++ks)
            Bf[c][ks] = *(const half8*)(WT + (c * 16 + x15) * EDGE_IN + ks * 32 + quad * 8);

    float gc[8], bc[8];
    #pragma unroll
    for (int c = 0; c < 8; ++c) { gc[c] = g[16 * c + x15]; bc[c] = b[16 * c + x15]; }

    if (t < 64)            lperm[t]       = perm[base + t];
    else if (t < 128)      lsrc[t - 64]   = psrc[base + t - 64];
    else if (t < 192)      ldst[t - 128]  = pdst[base + t - 128];
    __syncthreads();

    // stage 64 gathered EF rows (256B each) fp32 -> fp16
    #pragma unroll
    for (int j = 0; j < 4; ++j) {
        int idx = j * 1024 + t * 4;
        int r = idx >> 6, kk = idx & 63;
        const float4 v = *(const float4*)(EF + (size_t)lperm[r] * EDGE_IN + kk);
        half4 h4;
        h4[0] = (_Float16)v.x; h4[1] = (_Float16)v.y;
        h4[2] = (_Float16)v.z; h4[3] = (_Float16)v.w;
        *(half4*)(lA + r * 72 + kk) = h4;
    }
    __syncthreads();

    f32x4 acc[8];
    #pragma unroll
    for (int c = 0; c < 8; ++c) acc[c] = (f32x4)(0.0f);
    #pragma unroll
    for (int ks = 0; ks < 2; ++ks) {
        half8 a = *(const half8*)(lA + (wave * 16 + x15) * 72 + ks * 32 + quad * 8);
        #pragma unroll
        for (int c = 0; c < 8; ++c)
            acc[c] = __builtin_amdgcn_mfma_f32_16x16x32_f16(a, Bf[c][ks], acc[c], 0, 0, 0);
    }

    float s[4], sq[4];
    #pragma unroll
    for (int r = 0; r < 4; ++r) { s[r] = 0.f; sq[r] = 0.f; }
    #pragma unroll
    for (int c = 0; c < 8; ++c)
        #pragma unroll
        for (int r = 0; r < 4; ++r) { float x = acc[c][r]; s[r] += x; sq[r] += x * x; }
    #pragma unroll
    for (int m = 1; m <= 8; m <<= 1)
        #pragma unroll
        for (int r = 0; r < 4; ++r) {
            s[r]  += __shfl_xor(s[r],  m, 64);
            sq[r] += __shfl_xor(sq[r], m, 64);
        }

    // he = exp(LN(acc)); prod = he * hv[src]; -> LDS (permuted col p = x15*8+c)
    #pragma unroll
    for (int r = 0; r < 4; ++r) {
        const int erow = wave * 16 + quad * 4 + r;
        const int se = lsrc[erow];
        const half8 hg = *(const half8*)(hv + (size_t)se * HID + x15 * 8);
        float mean = s[r] * (1.f / 128.f);
        float var  = sq[r] * (1.f / 128.f) - mean * mean;
        float rstd = rsqrtf(var + LN_EPS);
        f32x4 p0, p1;
        #pragma unroll
        for (int c = 0; c < 8; ++c) {
            float he = __expf((acc[c][r] - mean) * rstd * gc[c] + bc[c]);
            float pr = he * (float)hg[c];
            if (c < 4) p0[c] = pr; else p1[c - 4] = pr;
        }
        float* lp = lprod + erow * 128 + x15 * 8;
        *(f32x4*)lp = p0;
        *(f32x4*)(lp + 4) = p1;
    }
    __syncthreads();

    // Phase 2: segmented column sums.  Thread j < 128 owns permuted col j.
    if (t < 128) {
        const int j = t;
        float run = 0.f;
        int rs = 0;
        for (int r = 0; r < 64; ++r) {
            run += lprod[r * 128 + j];
            const bool close = (r == 63) || (ldst[r + 1] != ldst[r]);
            if (close) {
                const int d = ldst[r];
                const int segbeg = offs[d], segend = offs[d + 1];
                const long long v = llrintf(run * 4294967296.0f);   // 2^32 fixed
                long long* hp = h64 + (size_t)d * HID + j;
                if (segbeg == base + rs && segend == base + r + 1) {
                    *hp = v;                                        // sole owner
                } else {
                    atomicAdd((unsigned long long*)hp, (unsigned long long)v);
                }
                run = 0.f; rs = r + 1;
            }
        }
    }
}

// ---------------------------------------------------------------------------
// Out projection: out = LN(GELU(h @ Wout)).  h arrives as int64 fixed-point
// (scale 2^32) in permuted layout; un-permute + convert in LDS staging.
// ---------------------------------------------------------------------------
__global__ __launch_bounds__(256) void out_kernel(
    const long long* __restrict__ h64,
    const float* __restrict__ W,       // [128][16]
    const float* __restrict__ g, const float* __restrict__ b,
    float* __restrict__ out)
{
    __shared__ float lW[HID * OUTD];
    __shared__ float lh[16][HID];
    const int t = threadIdx.x;
    const int node0 = blockIdx.x * 16;

    for (int i = t; i < HID * OUTD; i += 256) lW[i] = W[i];
    for (int i = t; i < 16 * HID; i += 256) {
        int row = i >> 7, p = i & 127;
        int k = 16 * (p & 7) + (p >> 3);     // un-permute: p = x*8 + c -> k = 16c + x
        int grow = node0 + row;
        lh[row][k] = (grow < N_NODES)
                   ? (float)h64[(size_t)grow * HID + p] * 0x1p-32f
                   : 0.f;
    }
    __syncthreads();

    const int i = t >> 4, j = t & 15;
    float acc = 0.f;
    #pragma unroll 8
    for (int k = 0; k < HID; ++k)
        acc = fmaf(lh[i][k], lW[k * OUTD + j], acc);
    float x = gelu_exact(acc);
    float s = x, sq = x * x;
    #pragma unroll
    for (int m = 1; m <= 8; m <<= 1) {
        s  += __shfl_xor(s,  m, 64);
        sq += __shfl_xor(sq, m, 64);
    }
    float mean = s * (1.f / 16.f);
    float var  = sq * (1.f / 16.f) - mean * mean;
    float rstd = rsqrtf(var + LN_EPS);
    int grow = node0 + i;
    if (grow < N_NODES) out[grow * OUTD + j] = (x - mean) * rstd * g[j] + b[j];
}

// ---------------------------------------------------------------------------
// Single unconditional path; no ws_size-dependent behavior (tripwire lesson).
// hist (25.6MB, dead after place_kernel) overlays h64 (51.2MB) -> ws ~74MB.
// ---------------------------------------------------------------------------
extern "C" void kernel_launch(void* const* d_in, const int* in_sizes, int n_in,
                              void* d_out, int out_size, void* d_ws, size_t ws_size,
                              hipStream_t stream) {
    const float* node_feats = (const float*)d_in[0];
    const float* edge_feats = (const float*)d_in[1];
    const int*   src        = (const int*)d_in[2];
    const int*   dst        = (const int*)d_in[3];
    const float* W_node     = (const float*)d_in[4];
    const float* g_node     = (const float*)d_in[5];
    const float* b_node     = (const float*)d_in[6];
    const float* W_edge     = (const float*)d_in[7];
    const float* g_edge     = (const float*)d_in[8];
    const float* b_edge     = (const float*)d_in[9];
    const float* W_out      = (const float*)d_in[10];
    const float* g_out      = (const float*)d_in[11];
    const float* b_out      = (const float*)d_in[12];
    float* out = (float*)d_out;

    char* ws = (char*)d_ws;
    size_t o = 0;
    _Float16* hv  = (_Float16*)(ws + o); o += (size_t)N_NODES * HID * 2;        // 12.8 MB
    _Float16* WTn = (_Float16*)(ws + o); o += (size_t)HID * NODE_IN * 2;        // 64 KB
    _Float16* WTe = (_Float16*)(ws + o); o += (size_t)HID * EDGE_IN * 2;        // 16 KB
    int* tot  = (int*)(ws + o); o += (size_t)N_NODES * 4;                       // 200 KB
    int* offs = (int*)(ws + o); o += (size_t)(N_NODES + 16) * 4;                // 200 KB
    int* btot = (int*)(ws + o); o += 1024;
    int* perm = (int*)(ws + o); o += (size_t)N_EDGES * 4;                       // 3.2 MB
    int* psrc = (int*)(ws + o); o += (size_t)N_EDGES * 4;                       // 3.2 MB
    int* pdst = (int*)(ws + o); o += (size_t)N_EDGES * 4;                       // 3.2 MB
    o = (o + 511) & ~(size_t)511;
    long long* h64 = (long long*)(ws + o);                                      // 51.2 MB
    int* hist = (int*)h64;   // 25.6 MB, lifetime ends at place_kernel

    zero_kernel<<<2048, 256, 0, stream>>>((int4*)hist, NCHUNK * N_NODES / 4);
    setup_kernel<<<128, 256, 0, stream>>>(W_node, W_edge, WTn, WTe);
    node_kernel<<<(N_NODES + 63) / 64, 256, 0, stream>>>(node_feats, WTn, g_node, b_node, hv);
    hist_kernel<<<NCHUNK * 4, 256, 0, stream>>>(dst, hist);
    tot_kernel<<<(N_NODES + 255) / 256, 256, 0, stream>>>(hist, tot);
    scan1_kernel<<<49, 256, 0, stream>>>(tot, offs, btot);
    scan2_kernel<<<49, 256, 0, stream>>>(offs, btot);
    cursor_kernel<<<(N_NODES + 255) / 256, 256, 0, stream>>>(offs, hist);
    place_kernel<<<NCHUNK, 256, 0, stream>>>(src, dst, hist, perm, psrc, pdst);
    zero_kernel<<<2048, 256, 0, stream>>>((int4*)h64, (int)((size_t)N_NODES * HID * 8 / 16));
    fagg_kernel<<<N_EDGES / 64, 256, 0, stream>>>(edge_feats, perm, psrc, pdst, offs,
                                                  WTe, g_edge, b_edge, hv, h64);
    out_kernel<<<(N_NODES + 15) / 16, 256, 0, stream>>>(h64, W_out, g_out, b_out, out);
}

// Round 6
// 678.630 us; speedup vs baseline: 1.7255x; 1.2898x over previous
//
#include <hip/hip_runtime.h>

#define N_NODES 50000
#define N_EDGES 800000
#define NODE_IN 256
#define EDGE_IN 64
#define HID 128
#define OUTD 16
#define LN_EPS 1e-5f

typedef __attribute__((ext_vector_type(4))) float f32x4;
typedef __attribute__((ext_vector_type(8))) _Float16 half8;
typedef __attribute__((ext_vector_type(4))) _Float16 half4;

__device__ __forceinline__ float gelu_exact(float x) {
    return 0.5f * x * (1.0f + erff(x * 0.70710678118654752f));
}

// ---------------------------------------------------------------------------
// Zero helper (kernel, capture-safe).
// ---------------------------------------------------------------------------
__global__ __launch_bounds__(256) void zero_kernel(int4* __restrict__ p, int n4) {
    int i = blockIdx.x * 256 + threadIdx.x;
    const int stride = gridDim.x * 256;
    for (; i < n4; i += stride) p[i] = make_int4(0, 0, 0, 0);
}

// ---------------------------------------------------------------------------
// Setup: transpose weights to [col][k] fp16 (MFMA B fragments become 16B loads)
// ---------------------------------------------------------------------------
__global__ void setup_kernel(const float* __restrict__ Wn, const float* __restrict__ We,
                             _Float16* __restrict__ WTn, _Float16* __restrict__ WTe) {
    int t = blockIdx.x * blockDim.x + threadIdx.x;
    int stride = gridDim.x * blockDim.x;
    for (int i = t; i < HID * NODE_IN; i += stride) {
        int n = i >> 8, k = i & 255;
        WTn[i] = (_Float16)Wn[k * HID + n];
    }
    for (int i = t; i < HID * EDGE_IN; i += stride) {
        int n = i >> 6, k = i & 63;
        WTe[i] = (_Float16)We[k * HID + n];
    }
}

// ---------------------------------------------------------------------------
// Grouping (NOT a stable sort -- downstream aggregation is exact int64
// fixed-point, hence commutative: any within-segment order yields
// bit-identical h64.  Only the segment spans [offs[d], offs[d+1]) matter.)
// ---------------------------------------------------------------------------
__global__ __launch_bounds__(256) void count_kernel(const int* __restrict__ dst,
                                                    int* __restrict__ tot) {
    int e = blockIdx.x * 256 + threadIdx.x;
    if (e < N_EDGES) atomicAdd(&tot[dst[e]], 1);
}

__global__ __launch_bounds__(256) void scan1_kernel(const int* __restrict__ tot,
                                                    int* __restrict__ offs,
                                                    int* __restrict__ btot) {
    __shared__ int lsum[256];
    const int t = threadIdx.x;
    const int base = blockIdx.x * 1024 + t * 4;
    int v[4]; int s = 0;
    #pragma unroll
    for (int j = 0; j < 4; ++j) {
        int idx = base + j;
        v[j] = (idx < N_NODES) ? tot[idx] : 0;
        s += v[j];
    }
    lsum[t] = s;
    __syncthreads();
    for (int d = 1; d < 256; d <<= 1) {
        int x = (t >= d) ? lsum[t - d] : 0;
        __syncthreads();
        lsum[t] += x;
        __syncthreads();
    }
    int excl = lsum[t] - s;
    if (t == 255) btot[blockIdx.x] = lsum[255];
    int run = excl;
    #pragma unroll
    for (int j = 0; j < 4; ++j) {
        int idx = base + j;
        if (idx < N_NODES) offs[idx] = run;
        run += v[j];
    }
}

// adds block prefix; also initializes the placement cursor copy
__global__ __launch_bounds__(256) void scan2_kernel(int* __restrict__ offs,
                                                    const int* __restrict__ btot,
                                                    int* __restrict__ cur) {
    int s = 0;
    for (int i = 0; i < (int)blockIdx.x; ++i) s += btot[i];
    const int t = threadIdx.x;
    const int base = blockIdx.x * 1024 + t * 4;
    #pragma unroll
    for (int j = 0; j < 4; ++j) {
        int idx = base + j;
        if (idx < N_NODES) {
            int v = offs[idx] + s;
            offs[idx] = v;
            cur[idx] = v;
        }
    }
    if (blockIdx.x == 0 && t == 0) offs[N_NODES] = N_EDGES;
}

// E-parallel grouping placement.  pos assignment within a segment is racy,
// but every position in [offs[d], offs[d+1]) receives dst==d, and the
// downstream sum is exact-commutative -> output bit-deterministic.
__global__ __launch_bounds__(256) void place2_kernel(const int* __restrict__ src,
                                                     const int* __restrict__ dst,
                                                     int* __restrict__ cur,
                                                     int* __restrict__ perm,
                                                     int* __restrict__ psrc,
                                                     int* __restrict__ pdst) {
    int e = blockIdx.x * 256 + threadIdx.x;
    if (e < N_EDGES) {
        const int d = dst[e];
        const int pos = atomicAdd(&cur[d], 1);
        perm[pos] = e;
        psrc[pos] = src[e];
        pdst[pos] = d;
    }
}

// ---------------------------------------------------------------------------
// Node projection: hv = LN(GELU(X @ Wn)), stored fp16 PERMUTED:
// hv[row*128 + x*8 + c] = value at col (16c + x).
// ---------------------------------------------------------------------------
__global__ __launch_bounds__(256) void node_kernel(
    const float* __restrict__ X,
    const _Float16* __restrict__ WT,    // [HID][NODE_IN]
    const float* __restrict__ g, const float* __restrict__ b,
    _Float16* __restrict__ hv)
{
    __shared__ __align__(16) _Float16 lA[64 * 72];
    __shared__ __align__(16) _Float16 lB[128 * 72];

    const int t = threadIdx.x;
    const int wave = t >> 6, lane = t & 63;
    const int x15 = lane & 15, quad = lane >> 4;
    const int row0 = blockIdx.x * 64;

    float gc[8], bc[8];
    #pragma unroll
    for (int c = 0; c < 8; ++c) { gc[c] = g[16 * c + x15]; bc[c] = b[16 * c + x15]; }

    f32x4 acc[8];
    #pragma unroll
    for (int c = 0; c < 8; ++c) acc[c] = (f32x4)(0.0f);

    for (int kc = 0; kc < 4; ++kc) {
        const int k0 = kc * 64;
        __syncthreads();
        #pragma unroll
        for (int j = 0; j < 4; ++j) {
            int idx = j * 1024 + t * 4;
            int r = idx >> 6, kk = idx & 63;
            int grow = row0 + r;
            float4 v = make_float4(0.f, 0.f, 0.f, 0.f);
            if (grow < N_NODES) v = *(const float4*)(X + grow * NODE_IN + k0 + kk);
            half4 h4;
            h4[0] = (_Float16)v.x; h4[1] = (_Float16)v.y;
            h4[2] = (_Float16)v.z; h4[3] = (_Float16)v.w;
            *(half4*)(lA + r * 72 + kk) = h4;
        }
        #pragma unroll
        for (int j = 0; j < 4; ++j) {
            int idx = j * 2048 + t * 8;
            int n = idx >> 6, kk = idx & 63;
            half8 v = *(const half8*)(WT + n * NODE_IN + k0 + kk);
            *(half8*)(lB + n * 72 + kk) = v;
        }
        __syncthreads();
        #pragma unroll
        for (int ks = 0; ks < 2; ++ks) {
            half8 a = *(const half8*)(lA + (wave * 16 + x15) * 72 + ks * 32 + quad * 8);
            #pragma unroll
            for (int c = 0; c < 8; ++c) {
                half8 bb = *(const half8*)(lB + (c * 16 + x15) * 72 + ks * 32 + quad * 8);
                acc[c] = __builtin_amdgcn_mfma_f32_16x16x32_f16(a, bb, acc[c], 0, 0, 0);
            }
        }
    }

    float v[8][4], s[4], sq[4];
    #pragma unroll
    for (int r = 0; r < 4; ++r) { s[r] = 0.f; sq[r] = 0.f; }
    #pragma unroll
    for (int c = 0; c < 8; ++c)
        #pragma unroll
        for (int r = 0; r < 4; ++r) {
            float x = gelu_exact(acc[c][r]);
            v[c][r] = x; s[r] += x; sq[r] += x * x;
        }
    #pragma unroll
    for (int m = 1; m <= 8; m <<= 1)
        #pragma unroll
        for (int r = 0; r < 4; ++r) {
            s[r]  += __shfl_xor(s[r],  m, 64);
            sq[r] += __shfl_xor(sq[r], m, 64);
        }
    #pragma unroll
    for (int r = 0; r < 4; ++r) {
        int row = row0 + wave * 16 + quad * 4 + r;
        if (row >= N_NODES) continue;
        float mean = s[r] * (1.f / 128.f);
        float var  = sq[r] * (1.f / 128.f) - mean * mean;
        float rstd = rsqrtf(var + LN_EPS);
        half8 o;
        #pragma unroll
        for (int c = 0; c < 8; ++c)
            o[c] = (_Float16)((v[c][r] - mean) * rstd * gc[c] + bc[c]);
        *(half8*)(hv + row * HID + x15 * 8) = o;
    }
}

// ---------------------------------------------------------------------------
// Fused sorted-block aggregation.  Block = 64 consecutive GROUPED edge
// positions.  Phase 1 (eproj structure): gather EF[perm[pos]], MFMA edge
// projection, LN+exp -> he, multiply by hv[psrc[pos]], store products to LDS.
// Phase 2: per-column segmented reduction over the 64 rows by dst, with the
// quantization done PER PRODUCT so the int64 sum is fully commutative
// (bit-deterministic under any within-segment edge order).  Segments fully
// owned by this block -> plain store; block-spanning fragments -> int64
// atomicAdd.  h64 pre-zeroed; scale 2^32.
// ---------------------------------------------------------------------------
__global__ __launch_bounds__(256) void fagg_kernel(
    const float* __restrict__ EF,
    const int* __restrict__ perm, const int* __restrict__ psrc,
    const int* __restrict__ pdst, const int* __restrict__ offs,
    const _Float16* __restrict__ WT,
    const float* __restrict__ g, const float* __restrict__ b,
    const _Float16* __restrict__ hv,
    long long* __restrict__ h64)
{
    __shared__ __align__(16) _Float16 lA[64 * 72];
    __shared__ __align__(16) float lprod[64 * 128];   // 32 KB
    __shared__ int lperm[64];
    __shared__ int lsrc[64];
    __shared__ int ldst[64];

    const int t = threadIdx.x;
    const int wave = t >> 6, lane = t & 63;
    const int x15 = lane & 15, quad = lane >> 4;
    const int base = blockIdx.x * 64;               // grouped-position base

    half8 Bf[8][2];
    #pragma unroll
    for (int c = 0; c < 8; ++c)
        #pragma unroll
        for (int ks = 0; ks < 2; ++ks)
            Bf[c][ks] = *(const half8*)(WT + (c * 16 + x15) * EDGE_IN + ks * 32 + quad * 8);

    float gc[8], bc[8];
    #pragma unroll
    for (int c = 0; c < 8; ++c) { gc[c] = g[16 * c + x15]; bc[c] = b[16 * c + x15]; }

    if (t < 64)            lperm[t]       = perm[base + t];
    else if (t < 128)      lsrc[t - 64]   = psrc[base + t - 64];
    else if (t < 192)      ldst[t - 128]  = pdst[base + t - 128];
    __syncthreads();

    // stage 64 gathered EF rows (256B each) fp32 -> fp16
    #pragma unroll
    for (int j = 0; j < 4; ++j) {
        int idx = j * 1024 + t * 4;
        int r = idx >> 6, kk = idx & 63;
        const float4 v = *(const float4*)(EF + (size_t)lperm[r] * EDGE_IN + kk);
        half4 h4;
        h4[0] = (_Float16)v.x; h4[1] = (_Float16)v.y;
        h4[2] = (_Float16)v.z; h4[3] = (_Float16)v.w;
        *(half4*)(lA + r * 72 + kk) = h4;
    }
    __syncthreads();

    f32x4 acc[8];
    #pragma unroll
    for (int c = 0; c < 8; ++c) acc[c] = (f32x4)(0.0f);
    #pragma unroll
    for (int ks = 0; ks < 2; ++ks) {
        half8 a = *(const half8*)(lA + (wave * 16 + x15) * 72 + ks * 32 + quad * 8);
        #pragma unroll
        for (int c = 0; c < 8; ++c)
            acc[c] = __builtin_amdgcn_mfma_f32_16x16x32_f16(a, Bf[c][ks], acc[c], 0, 0, 0);
    }

    float s[4], sq[4];
    #pragma unroll
    for (int r = 0; r < 4; ++r) { s[r] = 0.f; sq[r] = 0.f; }
    #pragma unroll
    for (int c = 0; c < 8; ++c)
        #pragma unroll
        for (int r = 0; r < 4; ++r) { float x = acc[c][r]; s[r] += x; sq[r] += x * x; }
    #pragma unroll
    for (int m = 1; m <= 8; m <<= 1)
        #pragma unroll
        for (int r = 0; r < 4; ++r) {
            s[r]  += __shfl_xor(s[r],  m, 64);
            sq[r] += __shfl_xor(sq[r], m, 64);
        }

    // he = exp(LN(acc)); prod = he * hv[src]; -> LDS (permuted col p = x15*8+c)
    #pragma unroll
    for (int r = 0; r < 4; ++r) {
        const int erow = wave * 16 + quad * 4 + r;
        const int se = lsrc[erow];
        const half8 hg = *(const half8*)(hv + (size_t)se * HID + x15 * 8);
        float mean = s[r] * (1.f / 128.f);
        float var  = sq[r] * (1.f / 128.f) - mean * mean;
        float rstd = rsqrtf(var + LN_EPS);
        f32x4 p0, p1;
        #pragma unroll
        for (int c = 0; c < 8; ++c) {
            float he = __expf((acc[c][r] - mean) * rstd * gc[c] + bc[c]);
            float pr = he * (float)hg[c];
            if (c < 4) p0[c] = pr; else p1[c - 4] = pr;
        }
        float* lp = lprod + erow * 128 + x15 * 8;
        *(f32x4*)lp = p0;
        *(f32x4*)(lp + 4) = p1;
    }
    __syncthreads();

    // Phase 2: segmented column sums; quantize per product, sum in int64.
    if (t < 128) {
        const int j = t;
        long long run = 0;
        int rs = 0;
        for (int r = 0; r < 64; ++r) {
            run += llrintf(lprod[r * 128 + j] * 4294967296.0f);   // 2^32 fixed
            const bool close = (r == 63) || (ldst[r + 1] != ldst[r]);
            if (close) {
                const int d = ldst[r];
                const int segbeg = offs[d], segend = offs[d + 1];
                long long* hp = h64 + (size_t)d * HID + j;
                if (segbeg == base + rs && segend == base + r + 1) {
                    *hp = run;                                    // sole owner
                } else {
                    atomicAdd((unsigned long long*)hp, (unsigned long long)run);
                }
                run = 0; rs = r + 1;
            }
        }
    }
}

// ---------------------------------------------------------------------------
// Out projection: out = LN(GELU(h @ Wout)).  h arrives as int64 fixed-point
// (scale 2^32) in permuted layout; un-permute + convert in LDS staging.
// ---------------------------------------------------------------------------
__global__ __launch_bounds__(256) void out_kernel(
    const long long* __restrict__ h64,
    const float* __restrict__ W,       // [128][16]
    const float* __restrict__ g, const float* __restrict__ b,
    float* __restrict__ out)
{
    __shared__ float lW[HID * OUTD];
    __shared__ float lh[16][HID];
    const int t = threadIdx.x;
    const int node0 = blockIdx.x * 16;

    for (int i = t; i < HID * OUTD; i += 256) lW[i] = W[i];
    for (int i = t; i < 16 * HID; i += 256) {
        int row = i >> 7, p = i & 127;
        int k = 16 * (p & 7) + (p >> 3);     // un-permute: p = x*8 + c -> k = 16c + x
        int grow = node0 + row;
        lh[row][k] = (grow < N_NODES)
                   ? (float)h64[(size_t)grow * HID + p] * 0x1p-32f
                   : 0.f;
    }
    __syncthreads();

    const int i = t >> 4, j = t & 15;
    float acc = 0.f;
    #pragma unroll 8
    for (int k = 0; k < HID; ++k)
        acc = fmaf(lh[i][k], lW[k * OUTD + j], acc);
    float x = gelu_exact(acc);
    float s = x, sq = x * x;
    #pragma unroll
    for (int m = 1; m <= 8; m <<= 1) {
        s  += __shfl_xor(s,  m, 64);
        sq += __shfl_xor(sq, m, 64);
    }
    float mean = s * (1.f / 16.f);
    float var  = sq * (1.f / 16.f) - mean * mean;
    float rstd = rsqrtf(var + LN_EPS);
    int grow = node0 + i;
    if (grow < N_NODES) out[grow * OUTD + j] = (x - mean) * rstd * g[j] + b[j];
}

// ---------------------------------------------------------------------------
// Single unconditional path; no ws_size-dependent behavior (tripwire lesson).
// Counting-sort machinery replaced by atomic grouping (stability not needed:
// exact int64 accumulation is commutative).  ws ~74 MB.
// ---------------------------------------------------------------------------
extern "C" void kernel_launch(void* const* d_in, const int* in_sizes, int n_in,
                              void* d_out, int out_size, void* d_ws, size_t ws_size,
                              hipStream_t stream) {
    const float* node_feats = (const float*)d_in[0];
    const float* edge_feats = (const float*)d_in[1];
    const int*   src        = (const int*)d_in[2];
    const int*   dst        = (const int*)d_in[3];
    const float* W_node     = (const float*)d_in[4];
    const float* g_node     = (const float*)d_in[5];
    const float* b_node     = (const float*)d_in[6];
    const float* W_edge     = (const float*)d_in[7];
    const float* g_edge     = (const float*)d_in[8];
    const float* b_edge     = (const float*)d_in[9];
    const float* W_out      = (const float*)d_in[10];
    const float* g_out      = (const float*)d_in[11];
    const float* b_out      = (const float*)d_in[12];
    float* out = (float*)d_out;

    char* ws = (char*)d_ws;
    size_t o = 0;
    _Float16* hv  = (_Float16*)(ws + o); o += (size_t)N_NODES * HID * 2;        // 12.8 MB
    _Float16* WTn = (_Float16*)(ws + o); o += (size_t)HID * NODE_IN * 2;        // 64 KB
    _Float16* WTe = (_Float16*)(ws + o); o += (size_t)HID * EDGE_IN * 2;        // 16 KB
    int* tot  = (int*)(ws + o); o += (size_t)N_NODES * 4;                       // 200 KB
    int* offs = (int*)(ws + o); o += (size_t)(N_NODES + 16) * 4;                // 200 KB
    int* btot = (int*)(ws + o); o += 1024;
    int* cur  = (int*)(ws + o); o += (size_t)N_NODES * 4;                       // 200 KB
    int* perm = (int*)(ws + o); o += (size_t)N_EDGES * 4;                       // 3.2 MB
    int* psrc = (int*)(ws + o); o += (size_t)N_EDGES * 4;                       // 3.2 MB
    int* pdst = (int*)(ws + o); o += (size_t)N_EDGES * 4;                       // 3.2 MB
    o = (o + 511) & ~(size_t)511;
    long long* h64 = (long long*)(ws + o);                                      // 51.2 MB

    zero_kernel<<<49, 256, 0, stream>>>((int4*)tot, N_NODES / 4);
    setup_kernel<<<128, 256, 0, stream>>>(W_node, W_edge, WTn, WTe);
    node_kernel<<<(N_NODES + 63) / 64, 256, 0, stream>>>(node_feats, WTn, g_node, b_node, hv);
    count_kernel<<<N_EDGES / 256, 256, 0, stream>>>(dst, tot);
    scan1_kernel<<<49, 256, 0, stream>>>(tot, offs, btot);
    scan2_kernel<<<49, 256, 0, stream>>>(offs, btot, cur);
    place2_kernel<<<N_EDGES / 256, 256, 0, stream>>>(src, dst, cur, perm, psrc, pdst);
    zero_kernel<<<2048, 256, 0, stream>>>((int4*)h64, (int)((size_t)N_NODES * HID * 8 / 16));
    fagg_kernel<<<N_EDGES / 64, 256, 0, stream>>>(edge_feats, perm, psrc, pdst, offs,
                                                  WTe, g_edge, b_edge, hv, h64);
    out_kernel<<<(N_NODES + 15) / 16, 256, 0, stream>>>(h64, W_out, g_out, b_out, out);
}

// Round 7
// 632.406 us; speedup vs baseline: 1.8517x; 1.0731x over previous
//
#include <hip/hip_runtime.h>

#define N_NODES 50000
#define N_EDGES 800000
#define NODE_IN 256
#define EDGE_IN 64
#define HID 128
#define OUTD 16
#define LN_EPS 1e-5f

typedef __attribute__((ext_vector_type(4))) float f32x4;
typedef __attribute__((ext_vector_type(8))) _Float16 half8;
typedef __attribute__((ext_vector_type(4))) _Float16 half4;

__device__ __forceinline__ float gelu_exact(float x) {
    return 0.5f * x * (1.0f + erff(x * 0.70710678118654752f));
}

// ---------------------------------------------------------------------------
// Zero helper (kernel, capture-safe).
// ---------------------------------------------------------------------------
__global__ __launch_bounds__(256) void zero_kernel(int4* __restrict__ p, int n4) {
    int i = blockIdx.x * 256 + threadIdx.x;
    const int stride = gridDim.x * 256;
    for (; i < n4; i += stride) p[i] = make_int4(0, 0, 0, 0);
}

// ---------------------------------------------------------------------------
// Setup: transpose weights to [col][k] fp16 (MFMA B fragments become 16B loads)
// ---------------------------------------------------------------------------
__global__ void setup_kernel(const float* __restrict__ Wn, const float* __restrict__ We,
                             _Float16* __restrict__ WTn, _Float16* __restrict__ WTe) {
    int t = blockIdx.x * blockDim.x + threadIdx.x;
    int stride = gridDim.x * blockDim.x;
    for (int i = t; i < HID * NODE_IN; i += stride) {
        int n = i >> 8, k = i & 255;
        WTn[i] = (_Float16)Wn[k * HID + n];
    }
    for (int i = t; i < HID * EDGE_IN; i += stride) {
        int n = i >> 6, k = i & 63;
        WTe[i] = (_Float16)We[k * HID + n];
    }
}

// ---------------------------------------------------------------------------
// Grouping (NOT a stable sort -- downstream aggregation is exact int64
// fixed-point, hence commutative: any within-segment order yields
// bit-identical h64.  Only the segment spans [offs[d], offs[d+1]) matter.)
// ---------------------------------------------------------------------------
__global__ __launch_bounds__(256) void count_kernel(const int* __restrict__ dst,
                                                    int* __restrict__ tot) {
    int e = blockIdx.x * 256 + threadIdx.x;
    if (e < N_EDGES) atomicAdd(&tot[dst[e]], 1);
}

__global__ __launch_bounds__(256) void scan1_kernel(const int* __restrict__ tot,
                                                    int* __restrict__ offs,
                                                    int* __restrict__ btot) {
    __shared__ int lsum[256];
    const int t = threadIdx.x;
    const int base = blockIdx.x * 1024 + t * 4;
    int v[4]; int s = 0;
    #pragma unroll
    for (int j = 0; j < 4; ++j) {
        int idx = base + j;
        v[j] = (idx < N_NODES) ? tot[idx] : 0;
        s += v[j];
    }
    lsum[t] = s;
    __syncthreads();
    for (int d = 1; d < 256; d <<= 1) {
        int x = (t >= d) ? lsum[t - d] : 0;
        __syncthreads();
        lsum[t] += x;
        __syncthreads();
    }
    int excl = lsum[t] - s;
    if (t == 255) btot[blockIdx.x] = lsum[255];
    int run = excl;
    #pragma unroll
    for (int j = 0; j < 4; ++j) {
        int idx = base + j;
        if (idx < N_NODES) offs[idx] = run;
        run += v[j];
    }
}

// adds block prefix; also initializes the placement cursor copy
__global__ __launch_bounds__(256) void scan2_kernel(int* __restrict__ offs,
                                                    const int* __restrict__ btot,
                                                    int* __restrict__ cur) {
    int s = 0;
    for (int i = 0; i < (int)blockIdx.x; ++i) s += btot[i];
    const int t = threadIdx.x;
    const int base = blockIdx.x * 1024 + t * 4;
    #pragma unroll
    for (int j = 0; j < 4; ++j) {
        int idx = base + j;
        if (idx < N_NODES) {
            int v = offs[idx] + s;
            offs[idx] = v;
            cur[idx] = v;
        }
    }
    if (blockIdx.x == 0 && t == 0) offs[N_NODES] = N_EDGES;
}

// E-parallel grouping placement.  pos assignment within a segment is racy,
// but every position in [offs[d], offs[d+1]) receives dst==d, and the
// downstream sum is exact-commutative -> output bit-deterministic.
__global__ __launch_bounds__(256) void place2_kernel(const int* __restrict__ src,
                                                     const int* __restrict__ dst,
                                                     int* __restrict__ cur,
                                                     int* __restrict__ perm,
                                                     int* __restrict__ psrc,
                                                     int* __restrict__ pdst) {
    int e = blockIdx.x * 256 + threadIdx.x;
    if (e < N_EDGES) {
        const int d = dst[e];
        const int pos = atomicAdd(&cur[d], 1);
        perm[pos] = e;
        psrc[pos] = src[e];
        pdst[pos] = d;
    }
}

// ---------------------------------------------------------------------------
// Node projection: hv = LN(GELU(X @ Wn)), stored fp16 PERMUTED:
// hv[row*128 + x*8 + c] = value at col (16c + x).
// ---------------------------------------------------------------------------
__global__ __launch_bounds__(256) void node_kernel(
    const float* __restrict__ X,
    const _Float16* __restrict__ WT,    // [HID][NODE_IN]
    const float* __restrict__ g, const float* __restrict__ b,
    _Float16* __restrict__ hv)
{
    __shared__ __align__(16) _Float16 lA[64 * 72];
    __shared__ __align__(16) _Float16 lB[128 * 72];

    const int t = threadIdx.x;
    const int wave = t >> 6, lane = t & 63;
    const int x15 = lane & 15, quad = lane >> 4;
    const int row0 = blockIdx.x * 64;

    float gc[8], bc[8];
    #pragma unroll
    for (int c = 0; c < 8; ++c) { gc[c] = g[16 * c + x15]; bc[c] = b[16 * c + x15]; }

    f32x4 acc[8];
    #pragma unroll
    for (int c = 0; c < 8; ++c) acc[c] = (f32x4)(0.0f);

    for (int kc = 0; kc < 4; ++kc) {
        const int k0 = kc * 64;
        __syncthreads();
        #pragma unroll
        for (int j = 0; j < 4; ++j) {
            int idx = j * 1024 + t * 4;
            int r = idx >> 6, kk = idx & 63;
            int grow = row0 + r;
            float4 v = make_float4(0.f, 0.f, 0.f, 0.f);
            if (grow < N_NODES) v = *(const float4*)(X + grow * NODE_IN + k0 + kk);
            half4 h4;
            h4[0] = (_Float16)v.x; h4[1] = (_Float16)v.y;
            h4[2] = (_Float16)v.z; h4[3] = (_Float16)v.w;
            *(half4*)(lA + r * 72 + kk) = h4;
        }
        #pragma unroll
        for (int j = 0; j < 4; ++j) {
            int idx = j * 2048 + t * 8;
            int n = idx >> 6, kk = idx & 63;
            half8 v = *(const half8*)(WT + n * NODE_IN + k0 + kk);
            *(half8*)(lB + n * 72 + kk) = v;
        }
        __syncthreads();
        #pragma unroll
        for (int ks = 0; ks < 2; ++ks) {
            half8 a = *(const half8*)(lA + (wave * 16 + x15) * 72 + ks * 32 + quad * 8);
            #pragma unroll
            for (int c = 0; c < 8; ++c) {
                half8 bb = *(const half8*)(lB + (c * 16 + x15) * 72 + ks * 32 + quad * 8);
                acc[c] = __builtin_amdgcn_mfma_f32_16x16x32_f16(a, bb, acc[c], 0, 0, 0);
            }
        }
    }

    float v[8][4], s[4], sq[4];
    #pragma unroll
    for (int r = 0; r < 4; ++r) { s[r] = 0.f; sq[r] = 0.f; }
    #pragma unroll
    for (int c = 0; c < 8; ++c)
        #pragma unroll
        for (int r = 0; r < 4; ++r) {
            float x = gelu_exact(acc[c][r]);
            v[c][r] = x; s[r] += x; sq[r] += x * x;
        }
    #pragma unroll
    for (int m = 1; m <= 8; m <<= 1)
        #pragma unroll
        for (int r = 0; r < 4; ++r) {
            s[r]  += __shfl_xor(s[r],  m, 64);
            sq[r] += __shfl_xor(sq[r], m, 64);
        }
    #pragma unroll
    for (int r = 0; r < 4; ++r) {
        int row = row0 + wave * 16 + quad * 4 + r;
        if (row >= N_NODES) continue;
        float mean = s[r] * (1.f / 128.f);
        float var  = sq[r] * (1.f / 128.f) - mean * mean;
        float rstd = rsqrtf(var + LN_EPS);
        half8 o;
        #pragma unroll
        for (int c = 0; c < 8; ++c)
            o[c] = (_Float16)((v[c][r] - mean) * rstd * gc[c] + bc[c]);
        *(half8*)(hv + row * HID + x15 * 8) = o;
    }
}

// ---------------------------------------------------------------------------
// Fused grouped aggregation, register-run edition.
// Block = 64 consecutive grouped edge positions, 256 threads.
// Thread (wave,quad,x15) owns 4 CONSECUTIVE rows [wave*16+quad*4, +4) x 8
// columns: products are quantized per-product (llrintf * 2^32) and summed in
// int64 REGISTERS across each within-thread segment run -- no lprod LDS
// round-trip, no serial 128-thread phase.  Pieces combine through a small
// per-block lacc[seg][col] int64 table (seg id via wave-0 shfl prefix scan;
// avg ~5 segs/block, cap 16; rare overflow -> direct global atomics).
// Final flush: block-owned segments plain-store, spanning segments atomicAdd.
// All sums exact-commutative int64 -> bit-deterministic.
// ---------------------------------------------------------------------------
#define NSMAX 16

__global__ __launch_bounds__(256) void fagg_kernel(
    const float* __restrict__ EF,
    const int* __restrict__ perm, const int* __restrict__ psrc,
    const int* __restrict__ pdst, const int* __restrict__ offs,
    const _Float16* __restrict__ WT,
    const float* __restrict__ g, const float* __restrict__ b,
    const _Float16* __restrict__ hv,
    long long* __restrict__ h64)
{
    __shared__ __align__(16) _Float16 lA[64 * 72];            // 9.2 KB
    __shared__ unsigned long long lacc[NSMAX * 128];          // 16 KB
    __shared__ int lperm[64];
    __shared__ int lsrc[64];
    __shared__ int ldst[64];
    __shared__ int lseg[64];
    __shared__ int lsegfr[NSMAX];
    __shared__ int lseglr[NSMAX];
    __shared__ int lnseg;

    const int t = threadIdx.x;
    const int wave = t >> 6, lane = t & 63;
    const int x15 = lane & 15, quad = lane >> 4;
    const int base = blockIdx.x * 64;               // grouped-position base

    half8 Bf[8][2];
    #pragma unroll
    for (int c = 0; c < 8; ++c)
        #pragma unroll
        for (int ks = 0; ks < 2; ++ks)
            Bf[c][ks] = *(const half8*)(WT + (c * 16 + x15) * EDGE_IN + ks * 32 + quad * 8);

    float gc[8], bc[8];
    #pragma unroll
    for (int c = 0; c < 8; ++c) { gc[c] = g[16 * c + x15]; bc[c] = b[16 * c + x15]; }

    // Phase A: wave0 loads metadata; waves 1-3 zero the seg accumulator.
    if (t < 64) {
        lperm[t] = perm[base + t];
        lsrc[t]  = psrc[base + t];
        ldst[t]  = pdst[base + t];
    } else {
        for (int i = t - 64; i < NSMAX * 128; i += 192) lacc[i] = 0ull;
    }
    __syncthreads();

    // Phase B: stage 64 gathered EF rows (256B each) fp32 -> fp16 (all threads)
    #pragma unroll
    for (int j = 0; j < 4; ++j) {
        int idx = j * 1024 + t * 4;
        int r = idx >> 6, kk = idx & 63;
        const float4 v = *(const float4*)(EF + (size_t)lperm[r] * EDGE_IN + kk);
        half4 h4;
        h4[0] = (_Float16)v.x; h4[1] = (_Float16)v.y;
        h4[2] = (_Float16)v.z; h4[3] = (_Float16)v.w;
        *(half4*)(lA + r * 72 + kk) = h4;
    }
    // wave0: segment-id prefix scan over the 64 rows (LDS-only, overlaps
    // other waves' staging latency)
    if (t < 64) {
        const int bnd = (t > 0 && ldst[t] != ldst[t - 1]) ? 1 : 0;
        int sc = bnd;
        #pragma unroll
        for (int m = 1; m < 64; m <<= 1) {
            int o = __shfl_up(sc, m, 64);
            if (t >= m) sc += o;
        }
        lseg[t] = sc;
        if (sc < NSMAX) {
            if (bnd || t == 0) lsegfr[sc] = t;
            if (t == 63 || ldst[t + 1] != ldst[t]) lseglr[sc] = t;
        }
        if (t == 63) lnseg = sc + 1;
    }
    __syncthreads();

    const int nsg = lnseg;

    // MFMA edge projection
    f32x4 acc[8];
    #pragma unroll
    for (int c = 0; c < 8; ++c) acc[c] = (f32x4)(0.0f);
    #pragma unroll
    for (int ks = 0; ks < 2; ++ks) {
        half8 a = *(const half8*)(lA + (wave * 16 + x15) * 72 + ks * 32 + quad * 8);
        #pragma unroll
        for (int c = 0; c < 8; ++c)
            acc[c] = __builtin_amdgcn_mfma_f32_16x16x32_f16(a, Bf[c][ks], acc[c], 0, 0, 0);
    }

    // LN stats per row
    float s[4], sq[4];
    #pragma unroll
    for (int r = 0; r < 4; ++r) { s[r] = 0.f; sq[r] = 0.f; }
    #pragma unroll
    for (int c = 0; c < 8; ++c)
        #pragma unroll
        for (int r = 0; r < 4; ++r) { float x = acc[c][r]; s[r] += x; sq[r] += x * x; }
    #pragma unroll
    for (int m = 1; m <= 8; m <<= 1)
        #pragma unroll
        for (int r = 0; r < 4; ++r) {
            s[r]  += __shfl_xor(s[r],  m, 64);
            sq[r] += __shfl_xor(sq[r], m, 64);
        }

    // Phase C: per-thread register runs over 4 consecutive rows
    long long a8[8];
    #pragma unroll
    for (int c = 0; c < 8; ++c) a8[c] = 0;

    #pragma unroll
    for (int rr = 0; rr < 4; ++rr) {
        const int erow = wave * 16 + quad * 4 + rr;
        const int se = lsrc[erow];
        const half8 hg = *(const half8*)(hv + (size_t)se * HID + x15 * 8);
        const float mean = s[rr] * (1.f / 128.f);
        const float var  = sq[rr] * (1.f / 128.f) - mean * mean;
        const float rstd = rsqrtf(var + LN_EPS);
        #pragma unroll
        for (int c = 0; c < 8; ++c) {
            const float he = __expf((acc[c][rr] - mean) * rstd * gc[c] + bc[c]);
            const float pr = he * (float)hg[c];
            a8[c] += llrintf(pr * 4294967296.0f);   // 2^32 fixed, per-product
        }
        const int dcur = ldst[erow];
        const bool close = (rr == 3) || (ldst[erow + 1] != dcur);
        if (close) {
            if (nsg <= NSMAX) {
                const int sgi = lseg[erow];
                unsigned long long* lp = &lacc[sgi * 128 + x15 * 8];
                #pragma unroll
                for (int c = 0; c < 8; ++c)
                    atomicAdd(&lp[c], (unsigned long long)a8[c]);
            } else {
                long long* hp = h64 + (size_t)dcur * HID + x15 * 8;
                #pragma unroll
                for (int c = 0; c < 8; ++c)
                    atomicAdd((unsigned long long*)&hp[c], (unsigned long long)a8[c]);
            }
            #pragma unroll
            for (int c = 0; c < 8; ++c) a8[c] = 0;
        }
    }
    __syncthreads();

    // Phase D: flush seg accumulators (block-owned -> store, else atomic)
    if (nsg <= NSMAX) {
        const int tot = nsg * 128;
        for (int i = t; i < tot; i += 256) {
            const int sgi = i >> 7, col = i & 127;
            const int fr = lsegfr[sgi], lr = lseglr[sgi];
            const int d = ldst[fr];
            const long long v = (long long)lacc[sgi * 128 + col];
            long long* hp = h64 + (size_t)d * HID + col;
            if (offs[d] == base + fr && offs[d + 1] == base + lr + 1) *hp = v;
            else atomicAdd((unsigned long long*)hp, (unsigned long long)v);
        }
    }
}

// ---------------------------------------------------------------------------
// Out projection: out = LN(GELU(h @ Wout)).  h arrives as int64 fixed-point
// (scale 2^32) in permuted layout; un-permute + convert in LDS staging.
// ---------------------------------------------------------------------------
__global__ __launch_bounds__(256) void out_kernel(
    const long long* __restrict__ h64,
    const float* __restrict__ W,       // [128][16]
    const float* __restrict__ g, const float* __restrict__ b,
    float* __restrict__ out)
{
    __shared__ float lW[HID * OUTD];
    __shared__ float lh[16][HID];
    const int t = threadIdx.x;
    const int node0 = blockIdx.x * 16;

    for (int i = t; i < HID * OUTD; i += 256) lW[i] = W[i];
    for (int i = t; i < 16 * HID; i += 256) {
        int row = i >> 7, p = i & 127;
        int k = 16 * (p & 7) + (p >> 3);     // un-permute: p = x*8 + c -> k = 16c + x
        int grow = node0 + row;
        lh[row][k] = (grow < N_NODES)
                   ? (float)h64[(size_t)grow * HID + p] * 0x1p-32f
                   : 0.f;
    }
    __syncthreads();

    const int i = t >> 4, j = t & 15;
    float acc = 0.f;
    #pragma unroll 8
    for (int k = 0; k < HID; ++k)
        acc = fmaf(lh[i][k], lW[k * OUTD + j], acc);
    float x = gelu_exact(acc);
    float s = x, sq = x * x;
    #pragma unroll
    for (int m = 1; m <= 8; m <<= 1) {
        s  += __shfl_xor(s,  m, 64);
        sq += __shfl_xor(sq, m, 64);
    }
    float mean = s * (1.f / 16.f);
    float var  = sq * (1.f / 16.f) - mean * mean;
    float rstd = rsqrtf(var + LN_EPS);
    int grow = node0 + i;
    if (grow < N_NODES) out[grow * OUTD + j] = (x - mean) * rstd * g[j] + b[j];
}

// ---------------------------------------------------------------------------
// Single unconditional path; no ws_size-dependent behavior (tripwire lesson).
// ---------------------------------------------------------------------------
extern "C" void kernel_launch(void* const* d_in, const int* in_sizes, int n_in,
                              void* d_out, int out_size, void* d_ws, size_t ws_size,
                              hipStream_t stream) {
    const float* node_feats = (const float*)d_in[0];
    const float* edge_feats = (const float*)d_in[1];
    const int*   src        = (const int*)d_in[2];
    const int*   dst        = (const int*)d_in[3];
    const float* W_node     = (const float*)d_in[4];
    const float* g_node     = (const float*)d_in[5];
    const float* b_node     = (const float*)d_in[6];
    const float* W_edge     = (const float*)d_in[7];
    const float* g_edge     = (const float*)d_in[8];
    const float* b_edge     = (const float*)d_in[9];
    const float* W_out      = (const float*)d_in[10];
    const float* g_out      = (const float*)d_in[11];
    const float* b_out      = (const float*)d_in[12];
    float* out = (float*)d_out;

    char* ws = (char*)d_ws;
    size_t o = 0;
    _Float16* hv  = (_Float16*)(ws + o); o += (size_t)N_NODES * HID * 2;        // 12.8 MB
    _Float16* WTn = (_Float16*)(ws + o); o += (size_t)HID * NODE_IN * 2;        // 64 KB
    _Float16* WTe = (_Float16*)(ws + o); o += (size_t)HID * EDGE_IN * 2;        // 16 KB
    int* tot  = (int*)(ws + o); o += (size_t)N_NODES * 4;                       // 200 KB
    int* offs = (int*)(ws + o); o += (size_t)(N_NODES + 16) * 4;                // 200 KB
    int* btot = (int*)(ws + o); o += 1024;
    int* cur  = (int*)(ws + o); o += (size_t)N_NODES * 4;                       // 200 KB
    int* perm = (int*)(ws + o); o += (size_t)N_EDGES * 4;                       // 3.2 MB
    int* psrc = (int*)(ws + o); o += (size_t)N_EDGES * 4;                       // 3.2 MB
    int* pdst = (int*)(ws + o); o += (size_t)N_EDGES * 4;                       // 3.2 MB
    o = (o + 511) & ~(size_t)511;
    long long* h64 = (long long*)(ws + o);                                      // 51.2 MB

    zero_kernel<<<49, 256, 0, stream>>>((int4*)tot, N_NODES / 4);
    setup_kernel<<<128, 256, 0, stream>>>(W_node, W_edge, WTn, WTe);
    node_kernel<<<(N_NODES + 63) / 64, 256, 0, stream>>>(node_feats, WTn, g_node, b_node, hv);
    count_kernel<<<N_EDGES / 256, 256, 0, stream>>>(dst, tot);
    scan1_kernel<<<49, 256, 0, stream>>>(tot, offs, btot);
    scan2_kernel<<<49, 256, 0, stream>>>(offs, btot, cur);
    place2_kernel<<<N_EDGES / 256, 256, 0, stream>>>(src, dst, cur, perm, psrc, pdst);
    zero_kernel<<<2048, 256, 0, stream>>>((int4*)h64, (int)((size_t)N_NODES * HID * 8 / 16));
    fagg_kernel<<<N_EDGES / 64, 256, 0, stream>>>(edge_feats, perm, psrc, pdst, offs,
                                                  WTe, g_edge, b_edge, hv, h64);
    out_kernel<<<(N_NODES + 15) / 16, 256, 0, stream>>>(h64, W_out, g_out, b_out, out);
}